// Round 1
// baseline (104.759 us; speedup 1.0000x reference)
//
#include <hip/hip_runtime.h>
#include <math.h>

// Problem constants (from reference setup_inputs)
#define B_SZ 1024
#define C_SZ 1000
#define H_SZ 512

// ws layout (bytes):
//   [0,     4096)  int      j[1024]       argmax index per batch row
//   [4096,  8192)  float    ymax[1024]    row max of y
//   [8192, 12288)  float    wnorm[1024]   ||w_c||^2
//   [12288,16384)  unsigned ybot[1024]    order-encoded running max of y_bot

__device__ __forceinline__ unsigned enc_f(float f) {
    unsigned u = __float_as_uint(f);
    return (u & 0x80000000u) ? ~u : (u | 0x80000000u);
}
__device__ __forceinline__ float dec_f(unsigned u) {
    return (u & 0x80000000u) ? __uint_as_float(u ^ 0x80000000u)
                             : __uint_as_float(~u);
}
// enc(-inf) = ~0xFF800000 = 0x007FFFFF
#define ENC_NEG_INF 0x007FFFFFu

// ---------------------------------------------------------------------------
// K1: per-row argmax (first index on ties, like jnp.argmax) + row max.
// Also initializes the ybot atomic slots (ws is re-poisoned every call).
__global__ void k_argmax(const float* __restrict__ y, int* __restrict__ jv,
                         float* __restrict__ ymax, unsigned* __restrict__ ybot) {
    int b = blockIdx.x;
    const float* row = y + b * C_SZ;
    float best = -INFINITY;
    int bidx = 0x7fffffff;
    for (int c = threadIdx.x; c < C_SZ; c += 256) {
        float v = row[c];
        if (v > best) { best = v; bidx = c; }  // strided ascending -> keeps first
    }
    __shared__ float sv[256];
    __shared__ int si[256];
    sv[threadIdx.x] = best;
    si[threadIdx.x] = bidx;
    __syncthreads();
    for (int s = 128; s > 0; s >>= 1) {
        if (threadIdx.x < s) {
            float ov = sv[threadIdx.x + s];
            int oi = si[threadIdx.x + s];
            if (ov > sv[threadIdx.x] ||
                (ov == sv[threadIdx.x] && oi < si[threadIdx.x])) {
                sv[threadIdx.x] = ov;
                si[threadIdx.x] = oi;
            }
        }
        __syncthreads();
    }
    if (threadIdx.x == 0) {
        jv[b] = si[0];
        ymax[b] = sv[0];
        ybot[b] = ENC_NEG_INF;
    }
}

// ---------------------------------------------------------------------------
// K2: wnorm[c] = sum_h w[c,h]^2.  One wave per class row (512 floats).
__global__ void k_wnorm(const float* __restrict__ w, float* __restrict__ wnorm) {
    int wave = threadIdx.x >> 6;
    int lane = threadIdx.x & 63;
    int c = blockIdx.x * 4 + wave;
    if (c >= C_SZ) return;
    const float4* w4 = (const float4*)(w + c * H_SZ);  // 128 float4 per row
    float4 a = w4[lane];
    float4 b = w4[lane + 64];
    float s = a.x * a.x + a.y * a.y + a.z * a.z + a.w * a.w +
              b.x * b.x + b.y * b.y + b.z * b.z + b.w * b.w;
    for (int off = 32; off; off >>= 1) s += __shfl_down(s, off, 64);
    if (lane == 0) wnorm[c] = s;
}

// ---------------------------------------------------------------------------
// K3: fused gathered GEMM + epilogue.
//   dot[b,c] = <w[j_b,:], w[c,:]>   (64x64 tile per block, 4x4 per thread)
//   cand     = y[b,c] + eps*sqrt(max(L^2*(nj+nc-2dot),0)), -inf on argmax cols
//   reduce max over c-strip, atomicMax into ybot[b]; also copy y into out.
__global__ __launch_bounds__(256) void k_main(
    const float* __restrict__ y, const float* __restrict__ w,
    const float* __restrict__ eps_p, const float* __restrict__ lip_p,
    const int* __restrict__ jv, const float* __restrict__ ymax,
    const float* __restrict__ wnorm, unsigned* __restrict__ ybot,
    float* __restrict__ out) {
    // LDS tiles: [kk][m], row stride 68 floats (17 float4) -> 16B-aligned rows,
    // <=2-way bank aliasing on both the scatter-writes and b128 reads (free).
    __shared__ __align__(16) float As[16][68];
    __shared__ __align__(16) float Bs[16][68];

    const int t = threadIdx.x;
    const int tx = t & 15;   // c-quad
    const int ty = t >> 4;   // b-quad
    const int b0 = blockIdx.y * 64;
    const int c0 = blockIdx.x * 64;

    // Staging-load assignment: thread loads one float4 of row lm at k-offset lk.
    const int lm = t >> 2;        // 0..63
    const int lk = (t & 3) * 4;   // 0,4,8,12
    const int arow = jv[b0 + lm];           // gathered A row (stable across K)
    const int ccol = c0 + lm;
    const bool cvalid = ccol < C_SZ;
    const float* aptr = w + arow * H_SZ + lk;
    const float* bptr = w + (cvalid ? ccol : 0) * H_SZ + lk;

    float acc[4][4] = {};

    for (int k0 = 0; k0 < H_SZ; k0 += 16) {
        float4 av = *(const float4*)(aptr + k0);
        float4 bv = cvalid ? *(const float4*)(bptr + k0)
                           : make_float4(0.f, 0.f, 0.f, 0.f);
        __syncthreads();  // previous iteration's LDS reads complete
        As[lk + 0][lm] = av.x;
        As[lk + 1][lm] = av.y;
        As[lk + 2][lm] = av.z;
        As[lk + 3][lm] = av.w;
        Bs[lk + 0][lm] = bv.x;
        Bs[lk + 1][lm] = bv.y;
        Bs[lk + 2][lm] = bv.z;
        Bs[lk + 3][lm] = bv.w;
        __syncthreads();
#pragma unroll
        for (int kk = 0; kk < 16; ++kk) {
            float4 a4 = *(const float4*)&As[kk][ty * 4];
            float4 b4 = *(const float4*)&Bs[kk][tx * 4];
            float ar[4] = {a4.x, a4.y, a4.z, a4.w};
            float br[4] = {b4.x, b4.y, b4.z, b4.w};
#pragma unroll
            for (int i = 0; i < 4; ++i)
#pragma unroll
                for (int j = 0; j < 4; ++j) acc[i][j] += ar[i] * br[j];
        }
    }

    // Epilogue
    const float eps = *eps_p;
    const float L = *lip_p;
    const float L2 = L * L;
    float rowmax[4];
#pragma unroll
    for (int i = 0; i < 4; ++i) {
        const int b = b0 + ty * 4 + i;
        const int jb = jv[b];
        const float nj = wnorm[jb];
        const float ym = ymax[b];
        const float* yrow = y + b * C_SZ;
        float* orow = out + b * (C_SZ + 1);
        float m = -INFINITY;
#pragma unroll
        for (int jj = 0; jj < 4; ++jj) {
            const int c = c0 + tx * 4 + jj;
            if (c < C_SZ) {
                const float yv = yrow[c];
                orow[c] = yv;  // copy-through portion of the output
                const float sq = L2 * (nj + wnorm[c] - 2.0f * acc[i][jj]);
                const float K = sq > 0.0f ? sqrtf(sq) : 0.0f;
                const float cand = (yv == ym) ? -INFINITY : yv + eps * K;
                if (cand > m) m = cand;
            }
        }
        rowmax[i] = m;
    }
    // Max across the 16 tx lanes of this ty group (contiguous lanes in-wave).
#pragma unroll
    for (int off = 8; off; off >>= 1)
#pragma unroll
        for (int i = 0; i < 4; ++i)
            rowmax[i] = fmaxf(rowmax[i], __shfl_down(rowmax[i], off, 16));
    if (tx == 0) {
#pragma unroll
        for (int i = 0; i < 4; ++i)
            atomicMax(&ybot[b0 + ty * 4 + i], enc_f(rowmax[i]));
    }
}

// ---------------------------------------------------------------------------
// K4: decode y_bot into the last output column.
__global__ void k_final(const unsigned* __restrict__ ybot,
                        float* __restrict__ out) {
    int b = blockIdx.x * 256 + threadIdx.x;
    if (b < B_SZ) out[b * (C_SZ + 1) + C_SZ] = dec_f(ybot[b]);
}

// ---------------------------------------------------------------------------
extern "C" void kernel_launch(void* const* d_in, const int* in_sizes, int n_in,
                              void* d_out, int out_size, void* d_ws,
                              size_t ws_size, hipStream_t stream) {
    const float* y = (const float*)d_in[0];
    const float* w = (const float*)d_in[1];
    const float* eps = (const float*)d_in[2];
    const float* lip = (const float*)d_in[3];
    float* out = (float*)d_out;

    char* ws = (char*)d_ws;
    int* jv = (int*)ws;
    float* ymax = (float*)(ws + 4096);
    float* wnorm = (float*)(ws + 8192);
    unsigned* ybot = (unsigned*)(ws + 12288);

    k_argmax<<<B_SZ, 256, 0, stream>>>(y, jv, ymax, ybot);
    k_wnorm<<<(C_SZ + 3) / 4, 256, 0, stream>>>(w, wnorm);
    k_main<<<dim3(16, 16), 256, 0, stream>>>(y, w, eps, lip, jv, ymax, wnorm,
                                             ybot, out);
    k_final<<<(B_SZ + 255) / 256, 256, 0, stream>>>(ybot, out);
}